// Round 2
// baseline (2822.363 us; speedup 1.0000x reference)
//
#include <hip/hip_runtime.h>

#define HID 128

// out[n][m] = sum_k f(X[n][k]) * W[m][k]  for a 64-row tile, all 128 cols.
// If bias != nullptr, f(x) = prelu(x + bias[k], alpha[0]) (fuses previous layer's
// bias+PReLU into the staging load); else f(x) = x.
__global__ __launch_bounds__(256) void gemm_tiled(
    const float* __restrict__ X, const float* __restrict__ W,
    const float* __restrict__ bias, const float* __restrict__ alpha,
    float* __restrict__ out, int N, int K) {
    __shared__ float Xs[64][36];    // row pad 36 (16B-aligned rows)
    __shared__ float Ws[32][132];   // transposed W tile, pad 132 (16B-aligned rows)

    const int tid = threadIdx.x;
    const int tx = tid & 31;        // cols tx*4 .. tx*4+3
    const int ty = tid >> 5;        // rows ty*8 .. ty*8+7
    const int n0 = blockIdx.x * 64;
    const float a = (bias != nullptr) ? alpha[0] : 0.f;

    float acc[8][4];
#pragma unroll
    for (int i = 0; i < 8; ++i)
#pragma unroll
        for (int j = 0; j < 4; ++j) acc[i][j] = 0.f;

    for (int k0 = 0; k0 < K; k0 += 32) {
        __syncthreads();
        // stage X tile: 64 rows x 32 k = 512 float4 slots, 2 per thread
#pragma unroll
        for (int s = tid; s < 512; s += 256) {
            int row = s >> 3, kq = s & 7;
            int n = n0 + row;
            float4 v = make_float4(0.f, 0.f, 0.f, 0.f);
            if (n < N) v = *(const float4*)&X[(size_t)n * K + k0 + kq * 4];
            if (bias != nullptr) {
                const float4 b = *(const float4*)&bias[k0 + kq * 4];
                v.x += b.x; v.y += b.y; v.z += b.z; v.w += b.w;
                v.x = v.x >= 0.f ? v.x : a * v.x;
                v.y = v.y >= 0.f ? v.y : a * v.y;
                v.z = v.z >= 0.f ? v.z : a * v.z;
                v.w = v.w >= 0.f ? v.w : a * v.w;
            }
            *(float4*)&Xs[row][kq * 4] = v;
        }
        // stage W tile transposed: Ws[kk][m] = W[m][k0+kk]; 128 m x 8 kq = 1024 slots
#pragma unroll
        for (int s = tid; s < 1024; s += 256) {
            int m = s >> 3, kq = s & 7;
            float4 v = *(const float4*)&W[(size_t)m * K + k0 + kq * 4];
            Ws[kq * 4 + 0][m] = v.x;
            Ws[kq * 4 + 1][m] = v.y;
            Ws[kq * 4 + 2][m] = v.z;
            Ws[kq * 4 + 3][m] = v.w;
        }
        __syncthreads();
#pragma unroll
        for (int kk = 0; kk < 32; kk += 4) {
            float4 wv[4];
#pragma unroll
            for (int j = 0; j < 4; ++j) wv[j] = *(const float4*)&Ws[kk + j][tx * 4];
#pragma unroll
            for (int i = 0; i < 8; ++i) {
                float4 xv = *(const float4*)&Xs[ty * 8 + i][kk];
                acc[i][0] += xv.x * wv[0].x; acc[i][1] += xv.x * wv[0].y;
                acc[i][2] += xv.x * wv[0].z; acc[i][3] += xv.x * wv[0].w;
                acc[i][0] += xv.y * wv[1].x; acc[i][1] += xv.y * wv[1].y;
                acc[i][2] += xv.y * wv[1].z; acc[i][3] += xv.y * wv[1].w;
                acc[i][0] += xv.z * wv[2].x; acc[i][1] += xv.z * wv[2].y;
                acc[i][2] += xv.z * wv[2].z; acc[i][3] += xv.z * wv[2].w;
                acc[i][0] += xv.w * wv[3].x; acc[i][1] += xv.w * wv[3].y;
                acc[i][2] += xv.w * wv[3].z; acc[i][3] += xv.w * wv[3].w;
            }
        }
    }
#pragma unroll
    for (int i = 0; i < 8; ++i) {
        int n = n0 + ty * 8 + i;
        if (n < N) {
            float4 v = make_float4(acc[i][0], acc[i][1], acc[i][2], acc[i][3]);
            *(float4*)&out[(size_t)n * HID + tx * 4] = v;
        }
    }
}

// agg[dst[e]][j] += w[e] * fts[src[e]][j], 4 cols per thread via float4 gather
__global__ void spmm_scatter(const int* __restrict__ src, const int* __restrict__ dst,
                             const float* __restrict__ w, const float* __restrict__ fts,
                             float* __restrict__ agg, int E) {
    long long stride = (long long)gridDim.x * blockDim.x;
    long long total = (long long)E * 32;   // HID/4 groups per edge
    for (long long idx = (long long)blockIdx.x * blockDim.x + threadIdx.x; idx < total;
         idx += stride) {
        int e = (int)(idx >> 5);
        int q = (int)(idx & 31);
        int s = src[e], d = dst[e];
        float wt = w[e];
        float4 v = *(const float4*)&fts[(size_t)s * HID + q * 4];
        float* p = &agg[(size_t)d * HID + q * 4];
        atomicAdd(p + 0, wt * v.x);
        atomicAdd(p + 1, wt * v.y);
        atomicAdd(p + 2, wt * v.z);
        atomicAdd(p + 3, wt * v.w);
    }
}

// z = prelu(z + b) in place, single shared alpha
__global__ void bias_prelu(float* __restrict__ z, const float* __restrict__ b,
                           const float* __restrict__ a, int total) {
    float alpha = a[0];
    int stride = gridDim.x * blockDim.x;
    for (int idx = blockIdx.x * blockDim.x + threadIdx.x; idx < total; idx += stride) {
        float v = z[idx] + b[idx & (HID - 1)];
        z[idx] = v >= 0.f ? v : alpha * v;
    }
}

extern "C" void kernel_launch(void* const* d_in, const int* in_sizes, int n_in,
                              void* d_out, int out_size, void* d_ws, size_t ws_size,
                              hipStream_t stream) {
    const float* x  = (const float*)d_in[0];
    const int*   ei = (const int*)d_in[1];
    const float* ew = (const float*)d_in[2];
    const float* W1 = (const float*)d_in[3];
    const float* b1 = (const float*)d_in[4];
    const float* a1 = (const float*)d_in[5];
    const float* W2 = (const float*)d_in[6];
    const float* b2 = (const float*)d_in[7];
    const float* a2 = (const float*)d_in[8];
    float* out = (float*)d_out;

    int N = in_sizes[0] / 256;      // 50000
    int E = in_sizes[2];            // 800000
    const int* src = ei;
    const int* dst = ei + E;

    float* fts = (float*)d_ws;                  // N*HID floats
    float* agg = fts + (size_t)N * HID;         // N*HID floats

    size_t nbytes = (size_t)N * HID * sizeof(float);
    hipMemsetAsync(agg, 0, nbytes, stream);
    hipMemsetAsync(d_out, 0, nbytes, stream);

    int gblk = (N + 63) / 64;

    // ---- layer 1 ----
    gemm_tiled<<<gblk, 256, 0, stream>>>(x, W1, nullptr, nullptr, fts, N, 256);
    spmm_scatter<<<2048, 256, 0, stream>>>(src, dst, ew, fts, agg, E);
    // (bias1 + PReLU1 fused into gemm2's staging load)

    // ---- layer 2 ----
    gemm_tiled<<<gblk, 256, 0, stream>>>(agg, W2, b1, a1, fts, N, 128);
    spmm_scatter<<<2048, 256, 0, stream>>>(src, dst, ew, fts, out, E);
    bias_prelu<<<2048, 256, 0, stream>>>(out, b2, a2, N * HID);
}

// Round 3
// 398.235 us; speedup vs baseline: 7.0872x; 7.0872x over previous
//
#include <hip/hip_runtime.h>

#define HID 128

// ---------------- dense GEMM: out = f(X) @ W^T ----------------
// 64x128 tile per 256-thread block. If bias != nullptr, staging applies
// f(x) = prelu(x + bias[k], alpha[0]) (fuses previous layer's epilogue).
__global__ __launch_bounds__(256) void gemm_tiled(
    const float* __restrict__ X, const float* __restrict__ W,
    const float* __restrict__ bias, const float* __restrict__ alpha,
    float* __restrict__ out, int N, int K) {
    __shared__ float Xs[64][36];
    __shared__ float Ws[32][132];

    const int tid = threadIdx.x;
    const int tx = tid & 31;
    const int ty = tid >> 5;
    const int n0 = blockIdx.x * 64;
    const float a = (bias != nullptr) ? alpha[0] : 0.f;

    float acc[8][4];
#pragma unroll
    for (int i = 0; i < 8; ++i)
#pragma unroll
        for (int j = 0; j < 4; ++j) acc[i][j] = 0.f;

    for (int k0 = 0; k0 < K; k0 += 32) {
        __syncthreads();
#pragma unroll
        for (int s = tid; s < 512; s += 256) {
            int row = s >> 3, kq = s & 7;
            int n = n0 + row;
            float4 v = make_float4(0.f, 0.f, 0.f, 0.f);
            if (n < N) v = *(const float4*)&X[(size_t)n * K + k0 + kq * 4];
            if (bias != nullptr) {
                const float4 b = *(const float4*)&bias[k0 + kq * 4];
                v.x += b.x; v.y += b.y; v.z += b.z; v.w += b.w;
                v.x = v.x >= 0.f ? v.x : a * v.x;
                v.y = v.y >= 0.f ? v.y : a * v.y;
                v.z = v.z >= 0.f ? v.z : a * v.z;
                v.w = v.w >= 0.f ? v.w : a * v.w;
            }
            *(float4*)&Xs[row][kq * 4] = v;
        }
#pragma unroll
        for (int s = tid; s < 1024; s += 256) {
            int m = s >> 3, kq = s & 7;
            float4 v = *(const float4*)&W[(size_t)m * K + k0 + kq * 4];
            Ws[kq * 4 + 0][m] = v.x;
            Ws[kq * 4 + 1][m] = v.y;
            Ws[kq * 4 + 2][m] = v.z;
            Ws[kq * 4 + 3][m] = v.w;
        }
        __syncthreads();
#pragma unroll
        for (int kk = 0; kk < 32; kk += 4) {
            float4 wv[4];
#pragma unroll
            for (int j = 0; j < 4; ++j) wv[j] = *(const float4*)&Ws[kk + j][tx * 4];
#pragma unroll
            for (int i = 0; i < 8; ++i) {
                float4 xv = *(const float4*)&Xs[ty * 8 + i][kk];
                acc[i][0] += xv.x * wv[0].x; acc[i][1] += xv.x * wv[0].y;
                acc[i][2] += xv.x * wv[0].z; acc[i][3] += xv.x * wv[0].w;
                acc[i][0] += xv.y * wv[1].x; acc[i][1] += xv.y * wv[1].y;
                acc[i][2] += xv.y * wv[1].z; acc[i][3] += xv.y * wv[1].w;
                acc[i][0] += xv.z * wv[2].x; acc[i][1] += xv.z * wv[2].y;
                acc[i][2] += xv.z * wv[2].z; acc[i][3] += xv.z * wv[2].w;
                acc[i][0] += xv.w * wv[3].x; acc[i][1] += xv.w * wv[3].y;
                acc[i][2] += xv.w * wv[3].z; acc[i][3] += xv.w * wv[3].w;
            }
        }
    }
#pragma unroll
    for (int i = 0; i < 8; ++i) {
        int n = n0 + ty * 8 + i;
        if (n < N) {
            float4 v = make_float4(acc[i][0], acc[i][1], acc[i][2], acc[i][3]);
            *(float4*)&out[(size_t)n * HID + tx * 4] = v;
        }
    }
}

// ---------------- CSR build ----------------
__global__ void csr_count(const int* __restrict__ dst, int* __restrict__ cnt, int E) {
    int stride = gridDim.x * blockDim.x;
    for (int e = blockIdx.x * blockDim.x + threadIdx.x; e < E; e += stride)
        atomicAdd(&cnt[dst[e]], 1);
}

// per-1024-chunk exclusive scan; block totals to tops
__global__ __launch_bounds__(256) void scan_block(const int* __restrict__ cnt,
                                                  int* __restrict__ off,
                                                  int* __restrict__ tops, int n) {
    __shared__ int lds[256];
    int base = blockIdx.x * 1024 + threadIdx.x * 4;
    int v[4];
#pragma unroll
    for (int j = 0; j < 4; ++j) v[j] = (base + j < n) ? cnt[base + j] : 0;
    int tsum = v[0] + v[1] + v[2] + v[3];
    lds[threadIdx.x] = tsum;
    __syncthreads();
    int x = tsum;
    for (int ofs = 1; ofs < 256; ofs <<= 1) {
        int y = (threadIdx.x >= ofs) ? lds[threadIdx.x - ofs] : 0;
        __syncthreads();
        x += y;
        lds[threadIdx.x] = x;
        __syncthreads();
    }
    int run = x - tsum;  // exclusive prefix of this thread's 4-group
    if (threadIdx.x == 255) tops[blockIdx.x] = x;
#pragma unroll
    for (int j = 0; j < 4; ++j) {
        if (base + j < n) off[base + j] = run;
        run += v[j];
    }
}

__global__ __launch_bounds__(256) void scan_tops(int* __restrict__ tops, int nb) {
    __shared__ int lds[256];
    int t = threadIdx.x;
    int v = (t < nb) ? tops[t] : 0;
    lds[t] = v;
    __syncthreads();
    int x = v;
    for (int ofs = 1; ofs < 256; ofs <<= 1) {
        int y = (t >= ofs) ? lds[t - ofs] : 0;
        __syncthreads();
        x += y;
        lds[t] = x;
        __syncthreads();
    }
    if (t < nb) tops[t] = x - v;  // exclusive
}

__global__ void scan_add(int* __restrict__ off, const int* __restrict__ tops,
                         int* __restrict__ cursor, int n, int E) {
    int i = blockIdx.x * blockDim.x + threadIdx.x;
    if (i < n) {
        int o = off[i] + tops[i >> 10];
        off[i] = o;
        cursor[i] = o;
    } else if (i == n) {
        off[n] = E;
    }
}

__global__ void csr_fill(const int* __restrict__ src, const int* __restrict__ dst,
                         const float* __restrict__ w, int* __restrict__ cursor,
                         int* __restrict__ idx, float* __restrict__ wv, int E) {
    int stride = gridDim.x * blockDim.x;
    for (int e = blockIdx.x * blockDim.x + threadIdx.x; e < E; e += stride) {
        int d = dst[e];
        int p = atomicAdd(&cursor[d], 1);
        idx[p] = src[e];
        wv[p] = w[e];
    }
}

// ---------------- pull-mode SpMM: out[d] = sum_p wv[p]*fts[idx[p]] ----------------
// one 128-thread block per dst node; optional fused bias+PReLU epilogue
__global__ __launch_bounds__(128) void csr_gather(
    const int* __restrict__ off, const int* __restrict__ idx,
    const float* __restrict__ wv, const float* __restrict__ fts,
    float* __restrict__ out, const float* __restrict__ bias,
    const float* __restrict__ alpha, int N) {
    int d = blockIdx.x;
    int j = threadIdx.x;
    int p = off[d], end = off[d + 1];
    float acc = 0.f;
    if (p < end) {
        int s = idx[p];
        float wt = wv[p];
        for (; p < end;) {
            int s2 = 0;
            float w2 = 0.f;
            if (p + 1 < end) { s2 = idx[p + 1]; w2 = wv[p + 1]; }  // prefetch next meta
            acc += wt * fts[(size_t)s * HID + j];
            s = s2;
            wt = w2;
            ++p;
        }
    }
    if (bias != nullptr) {
        acc += bias[j];
        float a = alpha[0];
        acc = acc >= 0.f ? acc : a * acc;
    }
    out[(size_t)d * HID + j] = acc;
}

extern "C" void kernel_launch(void* const* d_in, const int* in_sizes, int n_in,
                              void* d_out, int out_size, void* d_ws, size_t ws_size,
                              hipStream_t stream) {
    const float* x  = (const float*)d_in[0];
    const int*   ei = (const int*)d_in[1];
    const float* ew = (const float*)d_in[2];
    const float* W1 = (const float*)d_in[3];
    const float* b1 = (const float*)d_in[4];
    const float* a1 = (const float*)d_in[5];
    const float* W2 = (const float*)d_in[6];
    const float* b2 = (const float*)d_in[7];
    const float* a2 = (const float*)d_in[8];
    float* out = (float*)d_out;

    int N = in_sizes[0] / 256;   // 50000
    int E = in_sizes[2];         // 800000
    const int* src = ei;
    const int* dst = ei + E;

    // workspace layout
    float* fts   = (float*)d_ws;                 // N*HID
    int*   cnt   = (int*)(fts + (size_t)N * HID);// N
    int*   off   = cnt + N;                      // N+1
    int*   cursor= off + N + 1;                  // N
    int*   tops  = cursor + N;                   // 256
    int*   idx   = tops + 256;                   // E
    float* wv    = (float*)(idx + E);            // E

    // ---- CSR build (once per call) ----
    hipMemsetAsync(cnt, 0, (size_t)N * sizeof(int), stream);
    csr_count<<<2048, 256, 0, stream>>>(dst, cnt, E);
    int nchunk = (N + 1023) / 1024;
    scan_block<<<nchunk, 256, 0, stream>>>(cnt, off, tops, N);
    scan_tops<<<1, 256, 0, stream>>>(tops, nchunk);
    scan_add<<<(N + 256) / 256, 256, 0, stream>>>(off, tops, cursor, N, E);
    csr_fill<<<2048, 256, 0, stream>>>(src, dst, ew, cursor, idx, wv, E);

    int gblk = (N + 63) / 64;

    // ---- layer 1 ----  (bias1+PReLU1 fused into gemm2 staging)
    gemm_tiled<<<gblk, 256, 0, stream>>>(x, W1, nullptr, nullptr, fts, N, 256);
    csr_gather<<<N, HID, 0, stream>>>(off, idx, wv, fts, out, nullptr, nullptr, N);

    // ---- layer 2 ----  (bias2+PReLU2 fused into gather epilogue)
    gemm_tiled<<<gblk, 256, 0, stream>>>(out, W2, b1, a1, fts, N, 128);
    csr_gather<<<N, HID, 0, stream>>>(off, idx, wv, fts, out, b2, a2, N);
}

// Round 4
// 288.314 us; speedup vs baseline: 9.7892x; 1.3813x over previous
//
#include <hip/hip_runtime.h>

#define HID 128

typedef unsigned int uint;
typedef unsigned short ushort;

__device__ __forceinline__ uint pack_bf16x2(float a, float b) {
    uint ua = __float_as_uint(a);
    ua += 0x7fffu + ((ua >> 16) & 1u);          // RNE
    uint ub = __float_as_uint(b);
    ub += 0x7fffu + ((ub >> 16) & 1u);
    return (ua >> 16) | (ub & 0xffff0000u);
}

// ---------------- dense GEMM: fts_bf16 = f(X) @ W^T ----------------
// 64x128 tile per 256-thread block. If bias != nullptr, staging applies
// f(x) = prelu(x + bias[k], alpha[0]) (fuses previous layer's epilogue).
__global__ __launch_bounds__(256) void gemm_tiled(
    const float* __restrict__ X, const float* __restrict__ W,
    const float* __restrict__ bias, const float* __restrict__ alpha,
    ushort* __restrict__ out, int N, int K) {
    __shared__ float Xs[64][36];
    __shared__ float Ws[32][132];

    const int tid = threadIdx.x;
    const int tx = tid & 31;
    const int ty = tid >> 5;
    const int n0 = blockIdx.x * 64;
    const float a = (bias != nullptr) ? alpha[0] : 0.f;

    float acc[8][4];
#pragma unroll
    for (int i = 0; i < 8; ++i)
#pragma unroll
        for (int j = 0; j < 4; ++j) acc[i][j] = 0.f;

    for (int k0 = 0; k0 < K; k0 += 32) {
        __syncthreads();
#pragma unroll
        for (int s = tid; s < 512; s += 256) {
            int row = s >> 3, kq = s & 7;
            int n = n0 + row;
            float4 v = make_float4(0.f, 0.f, 0.f, 0.f);
            if (n < N) v = *(const float4*)&X[(size_t)n * K + k0 + kq * 4];
            if (bias != nullptr) {
                const float4 b = *(const float4*)&bias[k0 + kq * 4];
                v.x += b.x; v.y += b.y; v.z += b.z; v.w += b.w;
                v.x = v.x >= 0.f ? v.x : a * v.x;
                v.y = v.y >= 0.f ? v.y : a * v.y;
                v.z = v.z >= 0.f ? v.z : a * v.z;
                v.w = v.w >= 0.f ? v.w : a * v.w;
            }
            *(float4*)&Xs[row][kq * 4] = v;
        }
#pragma unroll
        for (int s = tid; s < 1024; s += 256) {
            int m = s >> 3, kq = s & 7;
            float4 v = *(const float4*)&W[(size_t)m * K + k0 + kq * 4];
            Ws[kq * 4 + 0][m] = v.x;
            Ws[kq * 4 + 1][m] = v.y;
            Ws[kq * 4 + 2][m] = v.z;
            Ws[kq * 4 + 3][m] = v.w;
        }
        __syncthreads();
#pragma unroll
        for (int kk = 0; kk < 32; kk += 4) {
            float4 wv[4];
#pragma unroll
            for (int j = 0; j < 4; ++j) wv[j] = *(const float4*)&Ws[kk + j][tx * 4];
#pragma unroll
            for (int i = 0; i < 8; ++i) {
                float4 xv = *(const float4*)&Xs[ty * 8 + i][kk];
                acc[i][0] += xv.x * wv[0].x; acc[i][1] += xv.x * wv[0].y;
                acc[i][2] += xv.x * wv[0].z; acc[i][3] += xv.x * wv[0].w;
                acc[i][0] += xv.y * wv[1].x; acc[i][1] += xv.y * wv[1].y;
                acc[i][2] += xv.y * wv[1].z; acc[i][3] += xv.y * wv[1].w;
                acc[i][0] += xv.z * wv[2].x; acc[i][1] += xv.z * wv[2].y;
                acc[i][2] += xv.z * wv[2].z; acc[i][3] += xv.z * wv[2].w;
                acc[i][0] += xv.w * wv[3].x; acc[i][1] += xv.w * wv[3].y;
                acc[i][2] += xv.w * wv[3].z; acc[i][3] += xv.w * wv[3].w;
            }
        }
    }
#pragma unroll
    for (int i = 0; i < 8; ++i) {
        int n = n0 + ty * 8 + i;
        if (n < N) {
            uint lo = pack_bf16x2(acc[i][0], acc[i][1]);
            uint hi = pack_bf16x2(acc[i][2], acc[i][3]);
            *(uint2*)&out[(size_t)n * HID + tx * 4] = make_uint2(lo, hi);
        }
    }
}

// ---------------- CSR build ----------------
__global__ void csr_count(const int* __restrict__ dst, int* __restrict__ cnt, int E) {
    int stride = gridDim.x * blockDim.x;
    for (int e = blockIdx.x * blockDim.x + threadIdx.x; e < E; e += stride)
        atomicAdd(&cnt[dst[e]], 1);
}

__global__ __launch_bounds__(256) void scan_block(const int* __restrict__ cnt,
                                                  int* __restrict__ off,
                                                  int* __restrict__ tops, int n) {
    __shared__ int lds[256];
    int base = blockIdx.x * 1024 + threadIdx.x * 4;
    int v[4];
#pragma unroll
    for (int j = 0; j < 4; ++j) v[j] = (base + j < n) ? cnt[base + j] : 0;
    int tsum = v[0] + v[1] + v[2] + v[3];
    lds[threadIdx.x] = tsum;
    __syncthreads();
    int x = tsum;
    for (int ofs = 1; ofs < 256; ofs <<= 1) {
        int y = (threadIdx.x >= ofs) ? lds[threadIdx.x - ofs] : 0;
        __syncthreads();
        x += y;
        lds[threadIdx.x] = x;
        __syncthreads();
    }
    int run = x - tsum;
    if (threadIdx.x == 255) tops[blockIdx.x] = x;
#pragma unroll
    for (int j = 0; j < 4; ++j) {
        if (base + j < n) off[base + j] = run;
        run += v[j];
    }
}

__global__ __launch_bounds__(256) void scan_tops(int* __restrict__ tops, int nb) {
    __shared__ int lds[256];
    int t = threadIdx.x;
    int v = (t < nb) ? tops[t] : 0;
    lds[t] = v;
    __syncthreads();
    int x = v;
    for (int ofs = 1; ofs < 256; ofs <<= 1) {
        int y = (t >= ofs) ? lds[t - ofs] : 0;
        __syncthreads();
        x += y;
        lds[t] = x;
        __syncthreads();
    }
    if (t < nb) tops[t] = x - v;
}

__global__ void scan_add(int* __restrict__ off, const int* __restrict__ tops,
                         int* __restrict__ cursor, int n, int E) {
    int i = blockIdx.x * blockDim.x + threadIdx.x;
    if (i < n) {
        int o = off[i] + tops[i >> 10];
        off[i] = o;
        cursor[i] = o;
    } else if (i == n) {
        off[n] = E;
    }
}

__global__ void csr_fill(const int* __restrict__ src, const int* __restrict__ dst,
                         const float* __restrict__ w, int* __restrict__ cursor,
                         int2* __restrict__ edges, int E) {
    int stride = gridDim.x * blockDim.x;
    for (int e = blockIdx.x * blockDim.x + threadIdx.x; e < E; e += stride) {
        int d = dst[e];
        int p = atomicAdd(&cursor[d], 1);
        edges[p] = make_int2(src[e], __float_as_int(w[e]));
    }
}

// ---------------- pull-mode SpMM over bf16 features ----------------
// one wave per dst node; lane handles cols 2*lane, 2*lane+1 (4B load = whole
// 256B row per wave). Unroll 4 edges for MLP. Optional fused bias+PReLU.
__global__ __launch_bounds__(256) void csr_gather_bf16(
    const int* __restrict__ off, const int2* __restrict__ edges,
    const ushort* __restrict__ fts, float* __restrict__ out,
    const float* __restrict__ bias, const float* __restrict__ alpha, int N) {
    int d = blockIdx.x * 4 + (threadIdx.x >> 6);
    if (d >= N) return;
    int lane = threadIdx.x & 63;
    int p = off[d], end = off[d + 1];
    float acc0 = 0.f, acc1 = 0.f;

#define ROWU(e) (*((const uint*)(fts + (size_t)(e).x * HID) + lane))
#define LO(r) __uint_as_float((r) << 16)
#define HI(r) __uint_as_float((r) & 0xffff0000u)

    for (; p + 3 < end; p += 4) {
        int2 e0 = edges[p], e1 = edges[p + 1], e2 = edges[p + 2], e3 = edges[p + 3];
        uint r0 = ROWU(e0), r1 = ROWU(e1), r2 = ROWU(e2), r3 = ROWU(e3);
        float w0 = __int_as_float(e0.y), w1 = __int_as_float(e1.y);
        float w2 = __int_as_float(e2.y), w3 = __int_as_float(e3.y);
        acc0 += w0 * LO(r0) + w1 * LO(r1) + w2 * LO(r2) + w3 * LO(r3);
        acc1 += w0 * HI(r0) + w1 * HI(r1) + w2 * HI(r2) + w3 * HI(r3);
    }
    for (; p < end; ++p) {
        int2 e = edges[p];
        uint r = ROWU(e);
        float wt = __int_as_float(e.y);
        acc0 += wt * LO(r);
        acc1 += wt * HI(r);
    }
#undef ROWU
#undef LO
#undef HI

    if (bias != nullptr) {
        float a = alpha[0];
        acc0 += bias[lane * 2 + 0];
        acc1 += bias[lane * 2 + 1];
        acc0 = acc0 >= 0.f ? acc0 : a * acc0;
        acc1 = acc1 >= 0.f ? acc1 : a * acc1;
    }
    *(float2*)&out[(size_t)d * HID + lane * 2] = make_float2(acc0, acc1);
}

extern "C" void kernel_launch(void* const* d_in, const int* in_sizes, int n_in,
                              void* d_out, int out_size, void* d_ws, size_t ws_size,
                              hipStream_t stream) {
    const float* x  = (const float*)d_in[0];
    const int*   ei = (const int*)d_in[1];
    const float* ew = (const float*)d_in[2];
    const float* W1 = (const float*)d_in[3];
    const float* b1 = (const float*)d_in[4];
    const float* a1 = (const float*)d_in[5];
    const float* W2 = (const float*)d_in[6];
    const float* b2 = (const float*)d_in[7];
    const float* a2 = (const float*)d_in[8];
    float* out = (float*)d_out;

    int N = in_sizes[0] / 256;   // 50000
    int E = in_sizes[2];         // 800000
    const int* src = ei;
    const int* dst = ei + E;

    // workspace layout (fts first keeps edges 8B-aligned)
    ushort* fts   = (ushort*)d_ws;                    // N*HID bf16
    int2*   edges = (int2*)(fts + (size_t)N * HID);   // E
    int*    cnt   = (int*)(edges + E);                // N
    int*    off   = cnt + N;                          // N+1
    int*    cursor= off + N + 1;                      // N
    int*    tops  = cursor + N;                       // 256

    // ---- CSR build ----
    hipMemsetAsync(cnt, 0, (size_t)N * sizeof(int), stream);
    csr_count<<<2048, 256, 0, stream>>>(dst, cnt, E);
    int nchunk = (N + 1023) / 1024;
    scan_block<<<nchunk, 256, 0, stream>>>(cnt, off, tops, N);
    scan_tops<<<1, 256, 0, stream>>>(tops, nchunk);
    scan_add<<<(N + 256) / 256, 256, 0, stream>>>(off, tops, cursor, N, E);
    csr_fill<<<2048, 256, 0, stream>>>(src, dst, ew, cursor, edges, E);

    int gblk = (N + 63) / 64;
    int ggrid = (N + 3) / 4;

    // ---- layer 1 ---- (bias1+PReLU1 fused into gemm2 staging)
    gemm_tiled<<<gblk, 256, 0, stream>>>(x, W1, nullptr, nullptr, fts, N, 256);
    csr_gather_bf16<<<ggrid, 256, 0, stream>>>(off, edges, fts, out, nullptr, nullptr, N);

    // ---- layer 2 ---- (bias2+PReLU2 fused into gather epilogue)
    gemm_tiled<<<gblk, 256, 0, stream>>>(out, W2, b1, a1, fts, N, 128);
    csr_gather_bf16<<<ggrid, 256, 0, stream>>>(off, edges, fts, out, b2, a2, N);
}

// Round 5
// 227.349 us; speedup vs baseline: 12.4142x; 1.2682x over previous
//
#include <hip/hip_runtime.h>

#define HID 128

typedef unsigned int uint;
typedef unsigned short ushort;
typedef __attribute__((ext_vector_type(8))) short short8;
typedef __attribute__((ext_vector_type(4))) float f32x4;

__device__ __forceinline__ uint pack_bf16x2(float a, float b) {
    uint ua = __float_as_uint(a);
    ua += 0x7fffu + ((ua >> 16) & 1u);          // RNE
    uint ub = __float_as_uint(b);
    ub += 0x7fffu + ((ub >> 16) & 1u);
    return (ua >> 16) | (ub & 0xffff0000u);
}

__device__ __forceinline__ ushort bf16_of(float x) {
    uint u = __float_as_uint(x);
    u += 0x7fffu + ((u >> 16) & 1u);
    return (ushort)(u >> 16);
}

__device__ __forceinline__ float4 addbias_prelu(float4 v, float4 b, float a) {
    v.x += b.x; v.y += b.y; v.z += b.z; v.w += b.w;
    v.x = v.x >= 0.f ? v.x : a * v.x;
    v.y = v.y >= 0.f ? v.y : a * v.y;
    v.z = v.z >= 0.f ? v.z : a * v.z;
    v.w = v.w >= 0.f ? v.w : a * v.w;
    return v;
}

union FragAB { uint4 u; short8 s; };

// ---------------- W -> fragment-linear bf16 pre-pack ----------------
// Wb[((s*8+c)*64 + lane)*8 .. +7] = bf16(W[c*16 + (lane&15)][s*32 + (lane>>4)*8 + j])
// so the GEMM's B-frag load is one contiguous 16B dwordx4 per lane.
__global__ void w_to_frags(const float* __restrict__ W, ushort* __restrict__ Wb, int K) {
    int t = blockIdx.x * 256 + threadIdx.x;
    int total = (K / 32) * 8 * 64;
    if (t >= total) return;
    int lane = t & 63, f = t >> 6;
    int s = f >> 3, c = f & 7;
    int m = c * 16 + (lane & 15);
    int k0 = s * 32 + (lane >> 4) * 8;
    const float* wr = W + (size_t)m * K + k0;
    float4 a = *(const float4*)wr;
    float4 b = *(const float4*)(wr + 4);
    uint4 o = make_uint4(pack_bf16x2(a.x, a.y), pack_bf16x2(a.z, a.w),
                         pack_bf16x2(b.x, b.y), pack_bf16x2(b.z, b.w));
    *(uint4*)(Wb + (size_t)t * 8) = o;
}

// ---------------- MFMA GEMM: fts_bf16 = f(X) @ W^T ----------------
// 4 waves/block, wave = 16 rows x 128 cols. No LDS, no barriers: A-frags are
// contiguous 32B fp32 loads converted inline; B-frags are 16B loads from the
// fragment-packed, L2-resident Wb. FUSE applies prelu(x + bias, alpha) to A
// (previous layer's epilogue).
template <int K, bool FUSE>
__global__ __launch_bounds__(256) void gemm_mfma(
    const float* __restrict__ X, const ushort* __restrict__ Wb,
    const float* __restrict__ bias, const float* __restrict__ alpha,
    ushort* __restrict__ out, int N) {
    const int lane = threadIdx.x & 63;
    const int wid  = threadIdx.x >> 6;
    const int n0   = blockIdx.x * 64 + wid * 16;
    const int arow = n0 + (lane & 15);
    const bool okA = arow < N;
    const int kgrp = (lane >> 4) * 8;
    const float* xrow = X + (size_t)arow * K;
    const float a_ = FUSE ? alpha[0] : 0.f;

    f32x4 acc[8];
#pragma unroll
    for (int c = 0; c < 8; ++c) acc[c] = (f32x4){0.f, 0.f, 0.f, 0.f};

#pragma unroll
    for (int s = 0; s < K / 32; ++s) {
        const int k0 = s * 32 + kgrp;
        float4 va = make_float4(0.f, 0.f, 0.f, 0.f), vb = va;
        if (okA) {
            va = *(const float4*)(xrow + k0);
            vb = *(const float4*)(xrow + k0 + 4);
        }
        if (FUSE) {
            float4 ba = *(const float4*)(bias + k0);
            float4 bb = *(const float4*)(bias + k0 + 4);
            va = addbias_prelu(va, ba, a_);
            vb = addbias_prelu(vb, bb, a_);
        }
        FragAB af;
        af.u = make_uint4(pack_bf16x2(va.x, va.y), pack_bf16x2(va.z, va.w),
                          pack_bf16x2(vb.x, vb.y), pack_bf16x2(vb.z, vb.w));
#pragma unroll
        for (int c = 0; c < 8; ++c) {
            FragAB bfr;
            bfr.u = *(const uint4*)(Wb + (size_t)((s * 8 + c) * 64 + lane) * 8);
            acc[c] = __builtin_amdgcn_mfma_f32_16x16x32_bf16(af.s, bfr.s, acc[c], 0, 0, 0);
        }
    }
    // C/D layout: col = lane&15, row = (lane>>4)*4 + reg
    const int col = lane & 15;
    const int rbase = n0 + (lane >> 4) * 4;
#pragma unroll
    for (int c = 0; c < 8; ++c) {
#pragma unroll
        for (int r = 0; r < 4; ++r) {
            int n = rbase + r;
            if (n < N) out[(size_t)n * HID + c * 16 + col] = bf16_of(acc[c][r]);
        }
    }
}

// ---------------- CSR build ----------------
__global__ void csr_count(const int* __restrict__ dst, int* __restrict__ cnt, int E) {
    int stride = gridDim.x * blockDim.x;
    for (int e = blockIdx.x * blockDim.x + threadIdx.x; e < E; e += stride)
        atomicAdd(&cnt[dst[e]], 1);
}

__global__ __launch_bounds__(256) void scan_block(const int* __restrict__ cnt,
                                                  int* __restrict__ off,
                                                  int* __restrict__ tops, int n) {
    __shared__ int lds[256];
    int base = blockIdx.x * 1024 + threadIdx.x * 4;
    int v[4];
#pragma unroll
    for (int j = 0; j < 4; ++j) v[j] = (base + j < n) ? cnt[base + j] : 0;
    int tsum = v[0] + v[1] + v[2] + v[3];
    lds[threadIdx.x] = tsum;
    __syncthreads();
    int x = tsum;
    for (int ofs = 1; ofs < 256; ofs <<= 1) {
        int y = (threadIdx.x >= ofs) ? lds[threadIdx.x - ofs] : 0;
        __syncthreads();
        x += y;
        lds[threadIdx.x] = x;
        __syncthreads();
    }
    int run = x - tsum;
    if (threadIdx.x == 255) tops[blockIdx.x] = x;
#pragma unroll
    for (int j = 0; j < 4; ++j) {
        if (base + j < n) off[base + j] = run;
        run += v[j];
    }
}

__global__ __launch_bounds__(256) void scan_tops(int* __restrict__ tops, int nb) {
    __shared__ int lds[256];
    int t = threadIdx.x;
    int v = (t < nb) ? tops[t] : 0;
    lds[t] = v;
    __syncthreads();
    int x = v;
    for (int ofs = 1; ofs < 256; ofs <<= 1) {
        int y = (t >= ofs) ? lds[t - ofs] : 0;
        __syncthreads();
        x += y;
        lds[t] = x;
        __syncthreads();
    }
    if (t < nb) tops[t] = x - v;
}

__global__ void scan_add(int* __restrict__ off, const int* __restrict__ tops,
                         int* __restrict__ cursor, int n, int E) {
    int i = blockIdx.x * blockDim.x + threadIdx.x;
    if (i < n) {
        int o = off[i] + tops[i >> 10];
        off[i] = o;
        cursor[i] = o;
    } else if (i == n) {
        off[n] = E;
    }
}

__global__ void csr_fill(const int* __restrict__ src, const int* __restrict__ dst,
                         const float* __restrict__ w, int* __restrict__ cursor,
                         int2* __restrict__ edges, int E) {
    int stride = gridDim.x * blockDim.x;
    for (int e = blockIdx.x * blockDim.x + threadIdx.x; e < E; e += stride) {
        int d = dst[e];
        int p = atomicAdd(&cursor[d], 1);
        edges[p] = make_int2(src[e], __float_as_int(w[e]));
    }
}

// ---------------- pull-mode SpMM over bf16 features ----------------
__global__ __launch_bounds__(256) void csr_gather_bf16(
    const int* __restrict__ off, const int2* __restrict__ edges,
    const ushort* __restrict__ fts, float* __restrict__ out,
    const float* __restrict__ bias, const float* __restrict__ alpha, int N) {
    int d = blockIdx.x * 4 + (threadIdx.x >> 6);
    if (d >= N) return;
    int lane = threadIdx.x & 63;
    int p = off[d], end = off[d + 1];
    float acc0 = 0.f, acc1 = 0.f;

#define ROWU(e) (*((const uint*)(fts + (size_t)(e).x * HID) + lane))
#define LO(r) __uint_as_float((r) << 16)
#define HI(r) __uint_as_float((r) & 0xffff0000u)

    for (; p + 3 < end; p += 4) {
        int2 e0 = edges[p], e1 = edges[p + 1], e2 = edges[p + 2], e3 = edges[p + 3];
        uint r0 = ROWU(e0), r1 = ROWU(e1), r2 = ROWU(e2), r3 = ROWU(e3);
        float w0 = __int_as_float(e0.y), w1 = __int_as_float(e1.y);
        float w2 = __int_as_float(e2.y), w3 = __int_as_float(e3.y);
        acc0 += w0 * LO(r0) + w1 * LO(r1) + w2 * LO(r2) + w3 * LO(r3);
        acc1 += w0 * HI(r0) + w1 * HI(r1) + w2 * HI(r2) + w3 * HI(r3);
    }
    for (; p < end; ++p) {
        int2 e = edges[p];
        uint r = ROWU(e);
        float wt = __int_as_float(e.y);
        acc0 += wt * LO(r);
        acc1 += wt * HI(r);
    }
#undef ROWU
#undef LO
#undef HI

    if (bias != nullptr) {
        float a = alpha[0];
        acc0 += bias[lane * 2 + 0];
        acc1 += bias[lane * 2 + 1];
        acc0 = acc0 >= 0.f ? acc0 : a * acc0;
        acc1 = acc1 >= 0.f ? acc1 : a * acc1;
    }
    *(float2*)&out[(size_t)d * HID + lane * 2] = make_float2(acc0, acc1);
}

extern "C" void kernel_launch(void* const* d_in, const int* in_sizes, int n_in,
                              void* d_out, int out_size, void* d_ws, size_t ws_size,
                              hipStream_t stream) {
    const float* x  = (const float*)d_in[0];
    const int*   ei = (const int*)d_in[1];
    const float* ew = (const float*)d_in[2];
    const float* W1 = (const float*)d_in[3];
    const float* b1 = (const float*)d_in[4];
    const float* a1 = (const float*)d_in[5];
    const float* W2 = (const float*)d_in[6];
    const float* b2 = (const float*)d_in[7];
    const float* a2 = (const float*)d_in[8];
    float* out = (float*)d_out;

    int N = in_sizes[0] / 256;   // 50000
    int E = in_sizes[2];         // 800000
    const int* src = ei;
    const int* dst = ei + E;

    // workspace layout (16B-aligned chunks first)
    ushort* fts   = (ushort*)d_ws;                    // N*HID bf16
    int2*   edges = (int2*)(fts + (size_t)N * HID);   // E
    ushort* Wb1   = (ushort*)(edges + E);             // 128*256
    ushort* Wb2   = Wb1 + 128 * 256;                  // 128*128
    int*    cnt   = (int*)(Wb2 + 128 * 128);          // N
    int*    off   = cnt + N;                          // N+1
    int*    cursor= off + N + 1;                      // N
    int*    tops  = cursor + N;                       // 256

    // ---- W pre-pack (tiny, L2-resident afterwards) ----
    w_to_frags<<<16, 256, 0, stream>>>(W1, Wb1, 256);
    w_to_frags<<<8, 256, 0, stream>>>(W2, Wb2, 128);

    // ---- CSR build ----
    hipMemsetAsync(cnt, 0, (size_t)N * sizeof(int), stream);
    csr_count<<<2048, 256, 0, stream>>>(dst, cnt, E);
    int nchunk = (N + 1023) / 1024;
    scan_block<<<nchunk, 256, 0, stream>>>(cnt, off, tops, N);
    scan_tops<<<1, 256, 0, stream>>>(tops, nchunk);
    scan_add<<<(N + 256) / 256, 256, 0, stream>>>(off, tops, cursor, N, E);
    csr_fill<<<2048, 256, 0, stream>>>(src, dst, ew, cursor, edges, E);

    int gblk = (N + 63) / 64;
    int ggrid = (N + 3) / 4;

    // ---- layer 1 ---- (bias1+PReLU1 fused into gemm2's A-load)
    gemm_mfma<256, false><<<gblk, 256, 0, stream>>>(x, Wb1, nullptr, nullptr, fts, N);
    csr_gather_bf16<<<ggrid, 256, 0, stream>>>(off, edges, fts, out, nullptr, nullptr, N);

    // ---- layer 2 ---- (bias2+PReLU2 fused into gather epilogue)
    gemm_mfma<128, true><<<gblk, 256, 0, stream>>>(out, Wb2, b1, a1, fts, N);
    csr_gather_bf16<<<ggrid, 256, 0, stream>>>(off, edges, fts, out, b2, a2, N);
}